// Round 9
// baseline (527.495 us; speedup 1.0000x reference)
//
#include <hip/hip_runtime.h>
#include <hip/hip_bf16.h>

#define TT 4
#define FD 128          // F_IN == H == O == 128
#define CC 2
#define LSE_CH 32
#define WROW 264        // padded LDS row stride (elems): 528 B -> 4-bank shift/row

// binning parameters
#define NPB 64
#define NPB_SHIFT 6
#define NBUKMAX 1024
#define CAP 1536
#define BIN_TILE 2048   // 8 edges/thread @ 256 threads

typedef __attribute__((ext_vector_type(8))) short bf16x8;
typedef __attribute__((ext_vector_type(4))) float f32x4;
typedef __attribute__((ext_vector_type(2))) float f32x2;
typedef __attribute__((ext_vector_type(4))) float fvec4;   // true vector type for NT loads

__device__ __forceinline__ float bf2f(unsigned int h) {
    union { unsigned int u; float f; } v; v.u = h << 16; return v.f;
}
__device__ __forceinline__ unsigned short f2bf(float f) {
    union { float f; unsigned int u; } v; v.f = f;
    unsigned int u = v.u;
    unsigned int r = u + 0x7FFFu + ((u >> 16) & 1u);   // round-to-nearest-even
    return (unsigned short)(r >> 16);
}
__device__ __forceinline__ unsigned int pack2(float lo, float hi) {
    return ((unsigned int)f2bf(hi) << 16) | (unsigned int)f2bf(lo);
}
// packed bf16-pair -> f32x2: {u<<16, u&0xFFFF0000} (1 shift + 1 and), then
// accumulation is one v_pk_add_f32 per pair (vs 2 scalar v_add_f32).
__device__ __forceinline__ f32x2 bfpair(unsigned int u) {
    union { unsigned int x; float f; } lo, hi;
    lo.x = u << 16; hi.x = u & 0xFFFF0000u;
    return (f32x2){lo.f, hi.f};
}
__device__ __forceinline__ void add8v(f32x2* a, uint4 v) {
    a[0] += bfpair(v.x); a[1] += bfpair(v.y);
    a[2] += bfpair(v.z); a[3] += bfpair(v.w);
}
__device__ __forceinline__ fvec4 ntld_f4(const float* p) {
    return __builtin_nontemporal_load((const fvec4*)p);
}

// K-deep gather round: covers 4*K edges (4 edge-slots x K steps each).
template<int K>
__device__ __forceinline__ void gather_round(const unsigned short* xb,
                                             const unsigned short* col,
                                             int& e, int eg, f32x2* acc) {
    uint4 v[K];
    #pragma unroll
    for (int u = 0; u < K; ++u)
        v[u] = *(const uint4*)(xb + (size_t)col[e + 4 * u + eg] * FD);
    #pragma unroll
    for (int u = 0; u < K; ++u) add8v(acc, v[u]);
    e += 4 * K;
}

// ---------------- fused prep: CSR binning + f32->bf16 conversion ----------------
// bin (latency-bound, 1564 blocks) and conv (BW-bound, 12500 blocks) are
// independent (bdata has its own buffer) -> one fat kernel, co-resident.

__global__ __launch_bounds__(256)
void prep_kernel(const int* __restrict__ graph, int* __restrict__ gcount,
                 unsigned int* __restrict__ bdata, int e, int nbuk, int bpg, int binBlocks,
                 const float* __restrict__ fts, unsigned short* __restrict__ xT, int total8) {
    __shared__ int cnt[NBUKMAX];
    __shared__ int base[NBUKMAX];
    if ((int)blockIdx.x >= binBlocks) {
        // ---- conv part: pure linear cast; NT load (fts read-once), REGULAR store ----
        int tid = (blockIdx.x - binBlocks) * 256 + threadIdx.x;
        if (tid >= total8) return;
        const float* s = fts + (size_t)tid * 8;
        fvec4 a = ntld_f4(s);
        fvec4 b = ntld_f4(s + 4);
        uint4 o;
        o.x = pack2(a[0], a[1]); o.y = pack2(a[2], a[3]);
        o.z = pack2(b[0], b[1]); o.w = pack2(b[2], b[3]);
        *(uint4*)(xT + (size_t)tid * 8) = o;
        return;
    }
    // ---- bin part: 8 edges preloaded/thread, LDS bucket count + scatter ----
    int g = blockIdx.x / bpg;
    int bx = blockIdx.x - g * bpg;
    const int* src = graph + (size_t)g * 2 * e;
    const int* dst = src + e;
    int tbeg = bx * BIN_TILE;
    for (int i = threadIdx.x; i < nbuk; i += 256) cnt[i] = 0;

    int d[8], s[8];
    bool valid[8];
    #pragma unroll
    for (int u = 0; u < 8; ++u) {
        int i = tbeg + u * 256 + threadIdx.x;
        valid[u] = i < e;
        if (valid[u]) { d[u] = dst[i]; s[u] = src[i]; }
    }
    __syncthreads();
    #pragma unroll
    for (int u = 0; u < 8; ++u)
        if (valid[u]) atomicAdd(&cnt[d[u] >> NPB_SHIFT], 1);
    __syncthreads();
    for (int i = threadIdx.x; i < nbuk; i += 256) {
        int c = cnt[i];
        base[i] = (c > 0) ? atomicAdd(&gcount[g * nbuk + i], c) : 0;
        cnt[i] = 0;                         // reuse as cursor
    }
    __syncthreads();
    #pragma unroll
    for (int u = 0; u < 8; ++u) {
        if (valid[u]) {
            int b = d[u] >> NPB_SHIFT;
            int pos = base[b] + atomicAdd(&cnt[b], 1);
            if (pos < CAP)
                bdata[((size_t)g * nbuk + b) * CAP + pos] =
                    ((unsigned int)(d[u] & (NPB - 1)) << 16) | (unsigned int)s[u];
        }
    }
}

// ---------------- build: per-bucket CSR finalize, inline prefix over gcount ----------------

__global__ __launch_bounds__(256)
void build_kernel(const unsigned int* __restrict__ bdata, const int* __restrict__ gcount,
                  int* __restrict__ arr, unsigned short* __restrict__ col,
                  int n, int nbuk, int e) {
    int g = blockIdx.y;
    int b = blockIdx.x;
    int M = gcount[g * nbuk + b];
    if (M > CAP) M = CAP;
    // inline exclusive prefix: base = sum_{i<b} gcount[g][i]  (L2-hot reads)
    __shared__ int red[256];
    int pre = 0;
    for (int i = threadIdx.x; i < b; i += 256) pre += gcount[g * nbuk + i];
    red[threadIdx.x] = pre;
    __syncthreads();
    #pragma unroll
    for (int off = 128; off > 0; off >>= 1) {
        if (threadIdx.x < off) red[threadIdx.x] += red[threadIdx.x + off];
        __syncthreads();
    }
    int base = red[0];

    const unsigned int* rec = bdata + ((size_t)g * nbuk + b) * CAP;
    __shared__ int deg[NPB];
    __shared__ int cursor[NPB];
    if (threadIdx.x < NPB) deg[threadIdx.x] = 0;
    __syncthreads();
    for (int i = threadIdx.x; i < M; i += 256)
        atomicAdd(&deg[rec[i] >> 16], 1);
    __syncthreads();
    if (threadIdx.x < NPB) {
        int d = deg[threadIdx.x];
        int incl = d;
        #pragma unroll
        for (int off = 1; off < NPB; off <<= 1) {
            int t = __shfl_up(incl, off, 64);
            if ((int)threadIdx.x >= off) incl += t;
        }
        cursor[threadIdx.x] = base + incl - d;
        int node = b * NPB + threadIdx.x;
        if (node < n) arr[(size_t)g * n + node] = base + incl;   // end offset
    }
    __syncthreads();
    for (int i = threadIdx.x; i < M; i += 256) {
        unsigned int r = rec[i];
        int p = atomicAdd(&cursor[r >> 16], 1);
        if (p < e) col[(size_t)g * e + p] = (unsigned short)(r & 0xFFFF);
    }
}

// packs both weight sets: blockIdx.y selects (W1l,W1r)->wcat1 or (W2l,W2r)->wcat2
__global__ void pack_weights_kernel(const float* __restrict__ W1l, const float* __restrict__ W1r,
                                    const float* __restrict__ W2l, const float* __restrict__ W2r,
                                    unsigned short* __restrict__ o1, unsigned short* __restrict__ o2) {
    int i = blockIdx.x * blockDim.x + threadIdx.x;   // 128*256
    if (i >= 128 * 256) return;
    const float* Wl = blockIdx.y ? W2l : W1l;
    const float* Wr = blockIdx.y ? W2r : W1r;
    unsigned short* out = blockIdx.y ? o2 : o1;
    int j = i >> 8, k = i & 255;
    float v = (k < 128) ? Wl[j * 128 + k] : Wr[j * 128 + (k - 128)];
    out[i] = f2bf(v);
}

// ---------------- unified gather-mean, ONE dispatch for all 4 t-slices ----------------
// Blocks t-major so the instantaneous gather working set ~= one 12.8 MB slice.
// r8 measured: VALU 59% / mem 44% / occ 75% all sub-saturated -> per-wave chain
// latency is the bound. r9: TWO adjacent nodes per wave, rounds interleaved ->
// 2 independent load chains per wave (12 chains/SIMD at 6 waves). Shared arr
// read (endA==begB), consecutive output rows, Poisson(32) wave balance.

__global__ __launch_bounds__(256, 6)
void agg_kernel(const int* __restrict__ arr0, const unsigned short* __restrict__ col0,
                const unsigned short* __restrict__ x0, unsigned short* __restrict__ mean0,
                int n, int bpt, int strideArr, int strideCol) {
    int t = blockIdx.x / bpt;
    int nb = blockIdx.x - t * bpt;
    int pair = (nb << 2) + (threadIdx.x >> 6);
    int nodeA = pair << 1;
    if (nodeA >= n) return;
    int nodeB = nodeA + 1;
    bool hasB = nodeB < n;
    const int* arr = arr0 + (size_t)t * strideArr;
    const unsigned short* col = col0 + (size_t)t * strideCol;
    const unsigned short* x = x0 + (size_t)t * n * FD;
    unsigned short* mean = mean0 + (size_t)t * n * FD;

    int lane = threadIdx.x & 63;
    int eg = lane >> 4;                 // edge slot 0..3
    int fl = lane & 15;                 // 16B feature slice

    int begA = (nodeA == 0) ? 0 : arr[nodeA - 1];
    int endA = arr[nodeA];              // == begB
    int begB = hasB ? endA : 0;
    int endB = hasB ? arr[nodeB] : 0;

    f32x2 accA[4], accB[4];
    #pragma unroll
    for (int j = 0; j < 4; ++j) { accA[j] = (f32x2){0.f, 0.f}; accB[j] = (f32x2){0.f, 0.f}; }
    const unsigned short* xb = x + fl * 8;
    int eA = begA, eB = begB;
    // deep-degree loop (rare at mean deg 16); A/B rounds issue back-to-back
    while (eA + 32 <= endA || eB + 32 <= endB) {
        if (eA + 32 <= endA) gather_round<8>(xb, col, eA, eg, accA);
        if (eB + 32 <= endB) gather_round<8>(xb, col, eB, eg, accB);
    }
    // adaptive ladder, A/B interleaved so both chains stay in flight
    if (eA + 16 <= endA) gather_round<4>(xb, col, eA, eg, accA);
    if (eB + 16 <= endB) gather_round<4>(xb, col, eB, eg, accB);
    if (eA + 8 <= endA) gather_round<2>(xb, col, eA, eg, accA);
    if (eB + 8 <= endB) gather_round<2>(xb, col, eB, eg, accB);
    if (eA + 4 <= endA) gather_round<1>(xb, col, eA, eg, accA);
    if (eB + 4 <= endB) gather_round<1>(xb, col, eB, eg, accB);
    if (eA < endA) {                    // <=3 leftover edges: one predicated step
        int idx = eA + eg;
        if (idx < endA) add8v(accA, *(const uint4*)(xb + (size_t)col[idx] * FD));
    }
    if (eB < endB) {
        int idx = eB + eg;
        if (idx < endB) add8v(accB, *(const uint4*)(xb + (size_t)col[idx] * FD));
    }
    // cross-slot reduce (4 partials -> all lanes), both nodes
    #pragma unroll
    for (int j = 0; j < 4; ++j) {
        accA[j][0] += __shfl_xor(accA[j][0], 16);
        accA[j][1] += __shfl_xor(accA[j][1], 16);
        accA[j][0] += __shfl_xor(accA[j][0], 32);
        accA[j][1] += __shfl_xor(accA[j][1], 32);
        accB[j][0] += __shfl_xor(accB[j][0], 16);
        accB[j][1] += __shfl_xor(accB[j][1], 16);
        accB[j][0] += __shfl_xor(accB[j][0], 32);
        accB[j][1] += __shfl_xor(accB[j][1], 32);
    }
    if (eg == 0) {
        {
            int deg = endA - begA;
            float inv = 1.f / (float)(deg > 1 ? deg : 1);
            f32x2 r0 = accA[0] * inv, r1 = accA[1] * inv;
            f32x2 r2 = accA[2] * inv, r3 = accA[3] * inv;
            uint4 o;
            o.x = pack2(r0[0], r0[1]);
            o.y = pack2(r1[0], r1[1]);
            o.z = pack2(r2[0], r2[1]);
            o.w = pack2(r3[0], r3[1]);
            *(uint4*)(mean + (size_t)nodeA * FD + fl * 8) = o;
        }
        if (hasB) {
            int deg = endB - begB;
            float inv = 1.f / (float)(deg > 1 ? deg : 1);
            f32x2 r0 = accB[0] * inv, r1 = accB[1] * inv;
            f32x2 r2 = accB[2] * inv, r3 = accB[3] * inv;
            uint4 o;
            o.x = pack2(r0[0], r0[1]);
            o.y = pack2(r1[0], r1[1]);
            o.z = pack2(r2[0], r2[1]);
            o.w = pack2(r3[0], r3[1]);
            *(uint4*)(mean + (size_t)nodeB * FD + fl * 8) = o;
        }
    }
}

// ---------------- SAGE GEMM: LDS W, 64 rows/wave, depth-2 A-prefetch ----------------
// out = leaky_relu([Am|Ax] @ Wcat^T + bias). out may alias Am (each wave reads all its
// rows' A-frags before its epilogue stores). No __restrict__ on Am/out.
// A operands are cache-warm (just written by agg/conv) -> regular loads.

__global__ __launch_bounds__(256, 2)
void sage_gemm_kernel(const unsigned short* Am, const unsigned short* __restrict__ Ax,
                      const unsigned short* __restrict__ Wcat, const float* __restrict__ bias,
                      unsigned short* out, int mrows) {
    int wave = threadIdx.x >> 6;
    int lane = threadIdx.x & 63;
    int m = lane & 15, q = lane >> 4;
    int rowBase = blockIdx.x * 256 + wave * 64;

    int arow[4];
    #pragma unroll
    for (int g = 0; g < 4; ++g) {
        int r = rowBase + g * 16 + m;
        arow[g] = (r < mrows) ? r : (mrows - 1);
    }

    // issue first two A-steps BEFORE LDS fill so cold latency overlaps staging
    bf16x8 af[3][4];
    #pragma unroll
    for (int g = 0; g < 4; ++g)
        af[0][g] = *(const bf16x8*)(Am + (size_t)arow[g] * FD + 0 * 32 + q * 8);
    #pragma unroll
    for (int g = 0; g < 4; ++g)
        af[1][g] = *(const bf16x8*)(Am + (size_t)arow[g] * FD + 1 * 32 + q * 8);

    __shared__ unsigned short Wlds[128 * WROW];
    for (int i = threadIdx.x; i < 128 * 32; i += 256) {
        int row = i >> 5, seg = i & 31;
        *(uint4*)(&Wlds[row * WROW + seg * 8]) = *(const uint4*)(Wcat + row * 256 + seg * 8);
    }
    __syncthreads();

    f32x4 acc[4][8];
    #pragma unroll
    for (int g = 0; g < 4; ++g)
        #pragma unroll
        for (int ct = 0; ct < 8; ++ct) acc[g][ct] = (f32x4){0.f, 0.f, 0.f, 0.f};

    #pragma unroll
    for (int step = 0; step < 8; ++step) {
        if (step < 6) {
            const unsigned short* An = (step + 2 < 4) ? Am : Ax;
            int kan = ((step + 2) & 3) * 32 + q * 8;
            #pragma unroll
            for (int g = 0; g < 4; ++g)
                af[(step + 2) % 3][g] = *(const bf16x8*)(An + (size_t)arow[g] * FD + kan);
        }
        int kw = step * 32 + q * 8;
        bf16x8 bfrag[8];
        #pragma unroll
        for (int ct = 0; ct < 8; ++ct)
            bfrag[ct] = *(const bf16x8*)(&Wlds[(ct * 16 + m) * WROW + kw]);
        #pragma unroll
        for (int g = 0; g < 4; ++g)
            #pragma unroll
            for (int ct = 0; ct < 8; ++ct)
                acc[g][ct] = __builtin_amdgcn_mfma_f32_16x16x32_bf16(af[step % 3][g], bfrag[ct], acc[g][ct], 0, 0, 0);
    }

    #pragma unroll
    for (int g = 0; g < 4; ++g) {
        #pragma unroll
        for (int ct = 0; ct < 8; ++ct) {
            int colc = ct * 16 + m;
            float b = bias[colc];
            #pragma unroll
            for (int r = 0; r < 4; ++r) {
                int row = rowBase + g * 16 + q * 4 + r;
                if (row < mrows) {
                    float v = acc[g][ct][r] + b;
                    v = (v >= 0.f) ? v : 0.2f * v;
                    out[(size_t)row * FD + colc] = f2bf(v);
                }
            }
        }
    }
}

// ---------------- layer-2 GEMM fused with classifier (same structure) ----------------
// t-major rows: row = t*N + node, logits flat [t][node][c] -> base = row*CC.

__global__ __launch_bounds__(256, 2)
void gemm2_cls_kernel(const unsigned short* __restrict__ Am, const unsigned short* __restrict__ Ax,
                      const unsigned short* __restrict__ Wcat, const float* __restrict__ bias,
                      const float* __restrict__ Wc, const float* __restrict__ bc,
                      float* __restrict__ logits, int mrows) {
    int wave = threadIdx.x >> 6;
    int lane = threadIdx.x & 63;
    int m = lane & 15, q = lane >> 4;
    int rowBase = blockIdx.x * 256 + wave * 64;

    int arow[4];
    #pragma unroll
    for (int g = 0; g < 4; ++g) {
        int r = rowBase + g * 16 + m;
        arow[g] = (r < mrows) ? r : (mrows - 1);
    }

    bf16x8 af[3][4];
    #pragma unroll
    for (int g = 0; g < 4; ++g)
        af[0][g] = *(const bf16x8*)(Am + (size_t)arow[g] * FD + 0 * 32 + q * 8);
    #pragma unroll
    for (int g = 0; g < 4; ++g)
        af[1][g] = *(const bf16x8*)(Am + (size_t)arow[g] * FD + 1 * 32 + q * 8);

    __shared__ unsigned short Wlds[128 * WROW];
    for (int i = threadIdx.x; i < 128 * 32; i += 256) {
        int row = i >> 5, seg = i & 31;
        *(uint4*)(&Wlds[row * WROW + seg * 8]) = *(const uint4*)(Wcat + row * 256 + seg * 8);
    }
    __syncthreads();

    f32x4 acc[4][8];
    #pragma unroll
    for (int g = 0; g < 4; ++g)
        #pragma unroll
        for (int ct = 0; ct < 8; ++ct) acc[g][ct] = (f32x4){0.f, 0.f, 0.f, 0.f};

    #pragma unroll
    for (int step = 0; step < 8; ++step) {
        if (step < 6) {
            const unsigned short* An = (step + 2 < 4) ? Am : Ax;
            int kan = ((step + 2) & 3) * 32 + q * 8;
            #pragma unroll
            for (int g = 0; g < 4; ++g)
                af[(step + 2) % 3][g] = *(const bf16x8*)(An + (size_t)arow[g] * FD + kan);
        }
        int kw = step * 32 + q * 8;
        bf16x8 bfrag[8];
        #pragma unroll
        for (int ct = 0; ct < 8; ++ct)
            bfrag[ct] = *(const bf16x8*)(&Wlds[(ct * 16 + m) * WROW + kw]);
        #pragma unroll
        for (int g = 0; g < 4; ++g)
            #pragma unroll
            for (int ct = 0; ct < 8; ++ct)
                acc[g][ct] = __builtin_amdgcn_mfma_f32_16x16x32_bf16(af[step % 3][g], bfrag[ct], acc[g][ct], 0, 0, 0);
    }

    float wc0[8], wc1[8], bb[8];
    #pragma unroll
    for (int ct = 0; ct < 8; ++ct) {
        wc0[ct] = Wc[ct * 16 + m];
        wc1[ct] = Wc[FD + ct * 16 + m];
        bb[ct]  = bias[ct * 16 + m];
    }
    float bc0 = bc[0], bc1 = bc[1];

    #pragma unroll
    for (int g = 0; g < 4; ++g) {
        #pragma unroll
        for (int r = 0; r < 4; ++r) {
            float p0 = 0.f, p1 = 0.f;
            #pragma unroll
            for (int ct = 0; ct < 8; ++ct) {
                float v = acc[g][ct][r] + bb[ct];
                v = (v >= 0.f) ? v : 0.2f * v;
                p0 += v * wc0[ct];
                p1 += v * wc1[ct];
            }
            #pragma unroll
            for (int off = 8; off > 0; off >>= 1) {
                p0 += __shfl_down(p0, off);
                p1 += __shfl_down(p1, off);
            }
            if (m == 0) {
                int row = rowBase + g * 16 + q * 4 + r;
                if (row < mrows) {
                    size_t base = (size_t)row * CC;
                    logits[base]     = p0 + bc0;
                    logits[base + 1] = p1 + bc1;
                }
            }
        }
    }
}

// ---------------- log_softmax over node axis (2-stage online) ----------------

__global__ __launch_bounds__(256)
void lse_partial_kernel(const float* __restrict__ logits, float* __restrict__ pm,
                        float* __restrict__ ps, int n) {
    int tc = blockIdx.y;
    int t = tc >> 1, c = tc & 1;
    const float* p = logits + (size_t)t * n * CC + c;
    float m = -1e30f, s = 0.f;
    for (int i = blockIdx.x * 256 + threadIdx.x; i < n; i += LSE_CH * 256) {
        float v = p[(size_t)i * CC];
        if (v > m) { s = s * __expf(m - v) + 1.f; m = v; }
        else s += __expf(v - m);
    }
    __shared__ float smm[256], sms[256];
    smm[threadIdx.x] = m; sms[threadIdx.x] = s;
    __syncthreads();
    for (int off = 128; off > 0; off >>= 1) {
        if (threadIdx.x < off) {
            float m2 = smm[threadIdx.x + off], s2 = sms[threadIdx.x + off];
            float M = fmaxf(smm[threadIdx.x], m2);
            sms[threadIdx.x] = sms[threadIdx.x] * __expf(smm[threadIdx.x] - M) + s2 * __expf(m2 - M);
            smm[threadIdx.x] = M;
        }
        __syncthreads();
    }
    if (threadIdx.x == 0) { pm[tc * LSE_CH + blockIdx.x] = smm[0]; ps[tc * LSE_CH + blockIdx.x] = sms[0]; }
}

// final LSE reduction fused into the subtraction kernel: each block re-reduces the
// 8 x 32 partials (2 KB reads/block) into LDS, then subtracts.
__global__ __launch_bounds__(256)
void sub_lse_kernel(const float* __restrict__ logits, const float* __restrict__ pm,
                    const float* __restrict__ ps, float* __restrict__ out, int total, int n) {
    __shared__ float slse[8];
    int tc = threadIdx.x >> 5;        // 8 groups of 32 lanes
    int l32 = threadIdx.x & 31;
    float m = pm[tc * LSE_CH + l32];
    float s = ps[tc * LSE_CH + l32];
    #pragma unroll
    for (int off = 16; off > 0; off >>= 1) {
        float m2 = __shfl_down(m, off, 32);
        float s2 = __shfl_down(s, off, 32);
        float M = fmaxf(m, m2);
        s = s * __expf(m - M) + s2 * __expf(m2 - M);
        m = M;
    }
    if (l32 == 0) slse[tc] = m + logf(s);
    __syncthreads();
    int i = blockIdx.x * 256 + threadIdx.x;
    if (i < total) {
        int c = i & 1;
        int t = i / (n * CC);
        out[i] = logits[i] - slse[t * CC + c];
    }
}

// ---------------- launch ----------------

extern "C" void kernel_launch(void* const* d_in, const int* in_sizes, int n_in,
                              void* d_out, int out_size, void* d_ws, size_t ws_size,
                              hipStream_t stream) {
    const int* graph = (const int*)d_in[0];
    const float* fts = (const float*)d_in[1];
    const float* W1l = (const float*)d_in[3];
    const float* b1  = (const float*)d_in[4];
    const float* W1r = (const float*)d_in[5];
    const float* W2l = (const float*)d_in[6];
    const float* b2  = (const float*)d_in[7];
    const float* W2r = (const float*)d_in[8];
    const float* Wc  = (const float*)d_in[9];
    const float* bc  = (const float*)d_in[10];
    float* out = (float*)d_out;

    const int T = TT;
    const int E = in_sizes[0] / (T * 2);
    const int N = in_sizes[1] / (T * FD);
    const int NBUK = (N + NPB - 1) >> NPB_SHIFT;

    size_t off = 0;
    auto alloc = [&](size_t bytes) -> char* {
        char* p = (char*)d_ws + off;
        off += (bytes + 511) & ~(size_t)511;
        return p;
    };
    int* arr_all = (int*)alloc((size_t)T * N * 4);
    unsigned short* col_all = (unsigned short*)alloc((size_t)T * E * 2);
    int* gcount = (int*)alloc((size_t)T * NBUK * 4);
    unsigned short* wcat1 = (unsigned short*)alloc(128 * 256 * 2);
    unsigned short* wcat2 = (unsigned short*)alloc(128 * 256 * 2);
    float* logits = (float*)alloc((size_t)T * N * CC * 4);
    float* pm  = (float*)alloc((size_t)T * CC * LSE_CH * 4);
    float* ps  = (float*)alloc((size_t)T * CC * LSE_CH * 4);
    // bdata has its own buffer (19.2 MB) so bin and conv are independent
    unsigned int* bdata = (unsigned int*)alloc((size_t)T * NBUK * CAP * 4);
    // t-major feature buffers, 51.2 MB each:
    // R1: xT (prep..gemm1) -> mean2T (agg2..gemm2)
    // R2: mean1T (agg1) -> ysT in-place (gemm1..gemm2)
    unsigned short* R1 = (unsigned short*)alloc((size_t)T * N * FD * 2);
    unsigned short* R2 = (unsigned short*)alloc((size_t)T * N * FD * 2);
    unsigned short* xT = R1;
    unsigned short* mean2T = R1;
    unsigned short* mean1T = R2;
    unsigned short* ysT = R2;

    dim3 pwgrid((128 * 256 + 255) / 256, 2);
    pack_weights_kernel<<<pwgrid, 256, 0, stream>>>(W1l, W1r, W2l, W2r, wcat1, wcat2);

    hipMemsetAsync(gcount, 0, (size_t)T * NBUK * 4, stream);

    // fused bin + conv
    int bpg = (E + BIN_TILE - 1) / BIN_TILE;
    int binBlocks = bpg * T;
    int total8 = T * N * 16;
    int convBlocks = (total8 + 255) / 256;
    prep_kernel<<<binBlocks + convBlocks, 256, 0, stream>>>(
        graph, gcount, bdata, E, NBUK, bpg, binBlocks, fts, xT, total8);

    // build (inline prefix scan over gcount)
    dim3 buildgrid(NBUK, T);
    build_kernel<<<buildgrid, 256, 0, stream>>>(bdata, gcount, arr_all, col_all, N, NBUK, E);

    // layer 1: one agg dispatch (t-major block order, 8 nodes/block), then one GEMM
    int bpt = (N + 7) / 8;
    agg_kernel<<<bpt * T, 256, 0, stream>>>(arr_all, col_all, xT, mean1T, N, bpt, N, E);
    int mrows = T * N;
    sage_gemm_kernel<<<(mrows + 255) / 256, 256, 0, stream>>>(mean1T, xT, wcat1, b1, ysT, mrows);

    // layer 2: one agg dispatch with the last graph (stride 0), fused GEMM+classifier
    const int* arrL = arr_all + (size_t)(T - 1) * N;
    const unsigned short* colL = col_all + (size_t)(T - 1) * E;
    agg_kernel<<<bpt * T, 256, 0, stream>>>(arrL, colL, ysT, mean2T, N, bpt, 0, 0);
    gemm2_cls_kernel<<<(mrows + 255) / 256, 256, 0, stream>>>(mean2T, ysT, wcat2, b2,
                                                              Wc, bc, logits, mrows);

    dim3 lgrid(LSE_CH, T * CC);
    lse_partial_kernel<<<lgrid, 256, 0, stream>>>(logits, pm, ps, N);
    int total = T * N * CC;
    sub_lse_kernel<<<(total + 255) / 256, 256, 0, stream>>>(logits, pm, ps, out, total, N);
}

// Round 10
// 515.181 us; speedup vs baseline: 1.0239x; 1.0239x over previous
//
#include <hip/hip_runtime.h>
#include <hip/hip_bf16.h>

#define TT 4
#define FD 128          // F_IN == H == O == 128
#define CC 2
#define LSE_CH 32
#define WROW 264        // padded LDS row stride (elems): 528 B -> 4-bank shift/row

// binning parameters
#define NPB 64
#define NPB_SHIFT 6
#define NBUKMAX 1024
#define CAP 1536
#define BIN_TILE 2048   // 8 edges/thread @ 256 threads

typedef __attribute__((ext_vector_type(8))) short bf16x8;
typedef __attribute__((ext_vector_type(4))) float f32x4;
typedef __attribute__((ext_vector_type(2))) float f32x2;
typedef __attribute__((ext_vector_type(4))) float fvec4;   // true vector type for NT loads

__device__ __forceinline__ float bf2f(unsigned int h) {
    union { unsigned int u; float f; } v; v.u = h << 16; return v.f;
}
__device__ __forceinline__ unsigned short f2bf(float f) {
    union { float f; unsigned int u; } v; v.f = f;
    unsigned int u = v.u;
    unsigned int r = u + 0x7FFFu + ((u >> 16) & 1u);   // round-to-nearest-even
    return (unsigned short)(r >> 16);
}
__device__ __forceinline__ unsigned int pack2(float lo, float hi) {
    return ((unsigned int)f2bf(hi) << 16) | (unsigned int)f2bf(lo);
}
// packed bf16-pair -> f32x2: {u<<16, u&0xFFFF0000} (1 shift + 1 and), then
// accumulation is one v_pk_add_f32 per pair (vs 2 scalar v_add_f32).
__device__ __forceinline__ f32x2 bfpair(unsigned int u) {
    union { unsigned int x; float f; } lo, hi;
    lo.x = u << 16; hi.x = u & 0xFFFF0000u;
    return (f32x2){lo.f, hi.f};
}
__device__ __forceinline__ void add8v(f32x2* a, uint4 v) {
    a[0] += bfpair(v.x); a[1] += bfpair(v.y);
    a[2] += bfpair(v.z); a[3] += bfpair(v.w);
}
__device__ __forceinline__ fvec4 ntld_f4(const float* p) {
    return __builtin_nontemporal_load((const fvec4*)p);
}

// K-deep gather round: covers 4*K edges (4 edge-slots x K steps each).
template<int K>
__device__ __forceinline__ void gather_round(const unsigned short* xb,
                                             const unsigned short* col,
                                             int& e, int eg, f32x2* acc) {
    uint4 v[K];
    #pragma unroll
    for (int u = 0; u < K; ++u)
        v[u] = *(const uint4*)(xb + (size_t)col[e + 4 * u + eg] * FD);
    #pragma unroll
    for (int u = 0; u < K; ++u) add8v(acc, v[u]);
    e += 4 * K;
}

// ---------------- fused prep: CSR binning + f32->bf16 conversion ----------------
// bin (latency-bound, 1564 blocks) and conv (BW-bound, 12500 blocks) are
// independent (bdata has its own buffer) -> one fat kernel, co-resident.

__global__ __launch_bounds__(256)
void prep_kernel(const int* __restrict__ graph, int* __restrict__ gcount,
                 unsigned int* __restrict__ bdata, int e, int nbuk, int bpg, int binBlocks,
                 const float* __restrict__ fts, unsigned short* __restrict__ xT, int total8) {
    __shared__ int cnt[NBUKMAX];
    __shared__ int base[NBUKMAX];
    if ((int)blockIdx.x >= binBlocks) {
        // ---- conv part: pure linear cast; NT load (fts read-once), REGULAR store ----
        int tid = (blockIdx.x - binBlocks) * 256 + threadIdx.x;
        if (tid >= total8) return;
        const float* s = fts + (size_t)tid * 8;
        fvec4 a = ntld_f4(s);
        fvec4 b = ntld_f4(s + 4);
        uint4 o;
        o.x = pack2(a[0], a[1]); o.y = pack2(a[2], a[3]);
        o.z = pack2(b[0], b[1]); o.w = pack2(b[2], b[3]);
        *(uint4*)(xT + (size_t)tid * 8) = o;
        return;
    }
    // ---- bin part: 8 edges preloaded/thread, LDS bucket count + scatter ----
    int g = blockIdx.x / bpg;
    int bx = blockIdx.x - g * bpg;
    const int* src = graph + (size_t)g * 2 * e;
    const int* dst = src + e;
    int tbeg = bx * BIN_TILE;
    for (int i = threadIdx.x; i < nbuk; i += 256) cnt[i] = 0;

    int d[8], s[8];
    bool valid[8];
    #pragma unroll
    for (int u = 0; u < 8; ++u) {
        int i = tbeg + u * 256 + threadIdx.x;
        valid[u] = i < e;
        if (valid[u]) { d[u] = dst[i]; s[u] = src[i]; }
    }
    __syncthreads();
    #pragma unroll
    for (int u = 0; u < 8; ++u)
        if (valid[u]) atomicAdd(&cnt[d[u] >> NPB_SHIFT], 1);
    __syncthreads();
    for (int i = threadIdx.x; i < nbuk; i += 256) {
        int c = cnt[i];
        base[i] = (c > 0) ? atomicAdd(&gcount[g * nbuk + i], c) : 0;
        cnt[i] = 0;                         // reuse as cursor
    }
    __syncthreads();
    #pragma unroll
    for (int u = 0; u < 8; ++u) {
        if (valid[u]) {
            int b = d[u] >> NPB_SHIFT;
            int pos = base[b] + atomicAdd(&cnt[b], 1);
            if (pos < CAP)
                bdata[((size_t)g * nbuk + b) * CAP + pos] =
                    ((unsigned int)(d[u] & (NPB - 1)) << 16) | (unsigned int)s[u];
        }
    }
}

// ---------------- build: per-bucket CSR finalize, inline prefix over gcount ----------------

__global__ __launch_bounds__(256)
void build_kernel(const unsigned int* __restrict__ bdata, const int* __restrict__ gcount,
                  int* __restrict__ arr, unsigned short* __restrict__ col,
                  int n, int nbuk, int e) {
    int g = blockIdx.y;
    int b = blockIdx.x;
    int M = gcount[g * nbuk + b];
    if (M > CAP) M = CAP;
    // inline exclusive prefix: base = sum_{i<b} gcount[g][i]  (L2-hot reads)
    __shared__ int red[256];
    int pre = 0;
    for (int i = threadIdx.x; i < b; i += 256) pre += gcount[g * nbuk + i];
    red[threadIdx.x] = pre;
    __syncthreads();
    #pragma unroll
    for (int off = 128; off > 0; off >>= 1) {
        if (threadIdx.x < off) red[threadIdx.x] += red[threadIdx.x + off];
        __syncthreads();
    }
    int base = red[0];

    const unsigned int* rec = bdata + ((size_t)g * nbuk + b) * CAP;
    __shared__ int deg[NPB];
    __shared__ int cursor[NPB];
    if (threadIdx.x < NPB) deg[threadIdx.x] = 0;
    __syncthreads();
    for (int i = threadIdx.x; i < M; i += 256)
        atomicAdd(&deg[rec[i] >> 16], 1);
    __syncthreads();
    if (threadIdx.x < NPB) {
        int d = deg[threadIdx.x];
        int incl = d;
        #pragma unroll
        for (int off = 1; off < NPB; off <<= 1) {
            int t = __shfl_up(incl, off, 64);
            if ((int)threadIdx.x >= off) incl += t;
        }
        cursor[threadIdx.x] = base + incl - d;
        int node = b * NPB + threadIdx.x;
        if (node < n) arr[(size_t)g * n + node] = base + incl;   // end offset
    }
    __syncthreads();
    for (int i = threadIdx.x; i < M; i += 256) {
        unsigned int r = rec[i];
        int p = atomicAdd(&cursor[r >> 16], 1);
        if (p < e) col[(size_t)g * e + p] = (unsigned short)(r & 0xFFFF);
    }
}

// packs both weight sets: blockIdx.y selects (W1l,W1r)->wcat1 or (W2l,W2r)->wcat2
__global__ void pack_weights_kernel(const float* __restrict__ W1l, const float* __restrict__ W1r,
                                    const float* __restrict__ W2l, const float* __restrict__ W2r,
                                    unsigned short* __restrict__ o1, unsigned short* __restrict__ o2) {
    int i = blockIdx.x * blockDim.x + threadIdx.x;   // 128*256
    if (i >= 128 * 256) return;
    const float* Wl = blockIdx.y ? W2l : W1l;
    const float* Wr = blockIdx.y ? W2r : W1r;
    unsigned short* out = blockIdx.y ? o2 : o1;
    int j = i >> 8, k = i & 255;
    float v = (k < 128) ? Wl[j * 128 + k] : Wr[j * 128 + (k - 128)];
    out[i] = f2bf(v);
}

// ---------------- unified gather-mean, ONE dispatch for all 4 t-slices ----------------
// Blocks t-major so the instantaneous gather working set ~= one 12.8 MB slice.
// Measured local optimum (r8, 101.5 us/dispatch): per-lane pointer addressing,
// packed f32x2 accumulate (v_pk_add_f32), degree-adaptive round depth
// (8-deep loop for deg>=32, then 4/2/1 + 1 predicated tail). r9's 2-node
// pairing regressed (ILP up but TLP down); r5/r6 NT + voffset regressed.
// Remaining ~100 us floor is cross-XCD gather line replication (structural).

__global__ __launch_bounds__(256)
void agg_kernel(const int* __restrict__ arr0, const unsigned short* __restrict__ col0,
                const unsigned short* __restrict__ x0, unsigned short* __restrict__ mean0,
                int n, int bpt, int strideArr, int strideCol) {
    int t = blockIdx.x / bpt;
    int nb = blockIdx.x - t * bpt;
    int node = (nb << 2) + (threadIdx.x >> 6);
    if (node >= n) return;
    const int* arr = arr0 + (size_t)t * strideArr;
    const unsigned short* col = col0 + (size_t)t * strideCol;
    const unsigned short* x = x0 + (size_t)t * n * FD;
    unsigned short* mean = mean0 + (size_t)t * n * FD;

    int lane = threadIdx.x & 63;
    int eg = lane >> 4;                 // edge slot 0..3
    int fl = lane & 15;                 // 16B feature slice
    int beg = (node == 0) ? 0 : arr[node - 1];
    int end = arr[node];
    f32x2 acc[4];
    #pragma unroll
    for (int j = 0; j < 4; ++j) acc[j] = (f32x2){0.f, 0.f};
    const unsigned short* xb = x + fl * 8;
    int e = beg;
    while (e + 32 <= end)               // deg >= 32: deep rounds for MLP
        gather_round<8>(xb, col, e, eg, acc);
    if (e + 16 <= end) gather_round<4>(xb, col, e, eg, acc);
    if (e +  8 <= end) gather_round<2>(xb, col, e, eg, acc);
    if (e +  4 <= end) gather_round<1>(xb, col, e, eg, acc);
    if (e < end) {                      // <=3 leftover edges: one predicated step
        int idx = e + eg;
        if (idx < end) {
            uint4 v = *(const uint4*)(xb + (size_t)col[idx] * FD);
            add8v(acc, v);
        }
    }
    // cross-slot reduce (4 partials -> all lanes)
    #pragma unroll
    for (int j = 0; j < 4; ++j) {
        acc[j][0] += __shfl_xor(acc[j][0], 16);
        acc[j][1] += __shfl_xor(acc[j][1], 16);
        acc[j][0] += __shfl_xor(acc[j][0], 32);
        acc[j][1] += __shfl_xor(acc[j][1], 32);
    }
    if (eg == 0) {
        int deg = end - beg;
        float inv = 1.f / (float)(deg > 1 ? deg : 1);
        f32x2 r0 = acc[0] * inv, r1 = acc[1] * inv;
        f32x2 r2 = acc[2] * inv, r3 = acc[3] * inv;
        uint4 o;
        o.x = pack2(r0[0], r0[1]);
        o.y = pack2(r1[0], r1[1]);
        o.z = pack2(r2[0], r2[1]);
        o.w = pack2(r3[0], r3[1]);
        *(uint4*)(mean + (size_t)node * FD + fl * 8) = o;
    }
}

// ---------------- SAGE GEMM: LDS W, 64 rows/wave, depth-2 A-prefetch ----------------
// out = leaky_relu([Am|Ax] @ Wcat^T + bias). out may alias Am (each wave reads all its
// rows' A-frags before its epilogue stores). No __restrict__ on Am/out.
// A operands are cache-warm (just written by agg/conv) -> regular loads.

__global__ __launch_bounds__(256, 2)
void sage_gemm_kernel(const unsigned short* Am, const unsigned short* __restrict__ Ax,
                      const unsigned short* __restrict__ Wcat, const float* __restrict__ bias,
                      unsigned short* out, int mrows) {
    int wave = threadIdx.x >> 6;
    int lane = threadIdx.x & 63;
    int m = lane & 15, q = lane >> 4;
    int rowBase = blockIdx.x * 256 + wave * 64;

    int arow[4];
    #pragma unroll
    for (int g = 0; g < 4; ++g) {
        int r = rowBase + g * 16 + m;
        arow[g] = (r < mrows) ? r : (mrows - 1);
    }

    // issue first two A-steps BEFORE LDS fill so cold latency overlaps staging
    bf16x8 af[3][4];
    #pragma unroll
    for (int g = 0; g < 4; ++g)
        af[0][g] = *(const bf16x8*)(Am + (size_t)arow[g] * FD + 0 * 32 + q * 8);
    #pragma unroll
    for (int g = 0; g < 4; ++g)
        af[1][g] = *(const bf16x8*)(Am + (size_t)arow[g] * FD + 1 * 32 + q * 8);

    __shared__ unsigned short Wlds[128 * WROW];
    for (int i = threadIdx.x; i < 128 * 32; i += 256) {
        int row = i >> 5, seg = i & 31;
        *(uint4*)(&Wlds[row * WROW + seg * 8]) = *(const uint4*)(Wcat + row * 256 + seg * 8);
    }
    __syncthreads();

    f32x4 acc[4][8];
    #pragma unroll
    for (int g = 0; g < 4; ++g)
        #pragma unroll
        for (int ct = 0; ct < 8; ++ct) acc[g][ct] = (f32x4){0.f, 0.f, 0.f, 0.f};

    #pragma unroll
    for (int step = 0; step < 8; ++step) {
        if (step < 6) {
            const unsigned short* An = (step + 2 < 4) ? Am : Ax;
            int kan = ((step + 2) & 3) * 32 + q * 8;
            #pragma unroll
            for (int g = 0; g < 4; ++g)
                af[(step + 2) % 3][g] = *(const bf16x8*)(An + (size_t)arow[g] * FD + kan);
        }
        int kw = step * 32 + q * 8;
        bf16x8 bfrag[8];
        #pragma unroll
        for (int ct = 0; ct < 8; ++ct)
            bfrag[ct] = *(const bf16x8*)(&Wlds[(ct * 16 + m) * WROW + kw]);
        #pragma unroll
        for (int g = 0; g < 4; ++g)
            #pragma unroll
            for (int ct = 0; ct < 8; ++ct)
                acc[g][ct] = __builtin_amdgcn_mfma_f32_16x16x32_bf16(af[step % 3][g], bfrag[ct], acc[g][ct], 0, 0, 0);
    }

    #pragma unroll
    for (int g = 0; g < 4; ++g) {
        #pragma unroll
        for (int ct = 0; ct < 8; ++ct) {
            int colc = ct * 16 + m;
            float b = bias[colc];
            #pragma unroll
            for (int r = 0; r < 4; ++r) {
                int row = rowBase + g * 16 + q * 4 + r;
                if (row < mrows) {
                    float v = acc[g][ct][r] + b;
                    v = (v >= 0.f) ? v : 0.2f * v;
                    out[(size_t)row * FD + colc] = f2bf(v);
                }
            }
        }
    }
}

// ---------------- layer-2 GEMM fused with classifier (same structure) ----------------
// t-major rows: row = t*N + node, logits flat [t][node][c] -> base = row*CC.

__global__ __launch_bounds__(256, 2)
void gemm2_cls_kernel(const unsigned short* __restrict__ Am, const unsigned short* __restrict__ Ax,
                      const unsigned short* __restrict__ Wcat, const float* __restrict__ bias,
                      const float* __restrict__ Wc, const float* __restrict__ bc,
                      float* __restrict__ logits, int mrows) {
    int wave = threadIdx.x >> 6;
    int lane = threadIdx.x & 63;
    int m = lane & 15, q = lane >> 4;
    int rowBase = blockIdx.x * 256 + wave * 64;

    int arow[4];
    #pragma unroll
    for (int g = 0; g < 4; ++g) {
        int r = rowBase + g * 16 + m;
        arow[g] = (r < mrows) ? r : (mrows - 1);
    }

    bf16x8 af[3][4];
    #pragma unroll
    for (int g = 0; g < 4; ++g)
        af[0][g] = *(const bf16x8*)(Am + (size_t)arow[g] * FD + 0 * 32 + q * 8);
    #pragma unroll
    for (int g = 0; g < 4; ++g)
        af[1][g] = *(const bf16x8*)(Am + (size_t)arow[g] * FD + 1 * 32 + q * 8);

    __shared__ unsigned short Wlds[128 * WROW];
    for (int i = threadIdx.x; i < 128 * 32; i += 256) {
        int row = i >> 5, seg = i & 31;
        *(uint4*)(&Wlds[row * WROW + seg * 8]) = *(const uint4*)(Wcat + row * 256 + seg * 8);
    }
    __syncthreads();

    f32x4 acc[4][8];
    #pragma unroll
    for (int g = 0; g < 4; ++g)
        #pragma unroll
        for (int ct = 0; ct < 8; ++ct) acc[g][ct] = (f32x4){0.f, 0.f, 0.f, 0.f};

    #pragma unroll
    for (int step = 0; step < 8; ++step) {
        if (step < 6) {
            const unsigned short* An = (step + 2 < 4) ? Am : Ax;
            int kan = ((step + 2) & 3) * 32 + q * 8;
            #pragma unroll
            for (int g = 0; g < 4; ++g)
                af[(step + 2) % 3][g] = *(const bf16x8*)(An + (size_t)arow[g] * FD + kan);
        }
        int kw = step * 32 + q * 8;
        bf16x8 bfrag[8];
        #pragma unroll
        for (int ct = 0; ct < 8; ++ct)
            bfrag[ct] = *(const bf16x8*)(&Wlds[(ct * 16 + m) * WROW + kw]);
        #pragma unroll
        for (int g = 0; g < 4; ++g)
            #pragma unroll
            for (int ct = 0; ct < 8; ++ct)
                acc[g][ct] = __builtin_amdgcn_mfma_f32_16x16x32_bf16(af[step % 3][g], bfrag[ct], acc[g][ct], 0, 0, 0);
    }

    float wc0[8], wc1[8], bb[8];
    #pragma unroll
    for (int ct = 0; ct < 8; ++ct) {
        wc0[ct] = Wc[ct * 16 + m];
        wc1[ct] = Wc[FD + ct * 16 + m];
        bb[ct]  = bias[ct * 16 + m];
    }
    float bc0 = bc[0], bc1 = bc[1];

    #pragma unroll
    for (int g = 0; g < 4; ++g) {
        #pragma unroll
        for (int r = 0; r < 4; ++r) {
            float p0 = 0.f, p1 = 0.f;
            #pragma unroll
            for (int ct = 0; ct < 8; ++ct) {
                float v = acc[g][ct][r] + bb[ct];
                v = (v >= 0.f) ? v : 0.2f * v;
                p0 += v * wc0[ct];
                p1 += v * wc1[ct];
            }
            #pragma unroll
            for (int off = 8; off > 0; off >>= 1) {
                p0 += __shfl_down(p0, off);
                p1 += __shfl_down(p1, off);
            }
            if (m == 0) {
                int row = rowBase + g * 16 + q * 4 + r;
                if (row < mrows) {
                    size_t base = (size_t)row * CC;
                    logits[base]     = p0 + bc0;
                    logits[base + 1] = p1 + bc1;
                }
            }
        }
    }
}

// ---------------- log_softmax over node axis (2-stage online) ----------------

__global__ __launch_bounds__(256)
void lse_partial_kernel(const float* __restrict__ logits, float* __restrict__ pm,
                        float* __restrict__ ps, int n) {
    int tc = blockIdx.y;
    int t = tc >> 1, c = tc & 1;
    const float* p = logits + (size_t)t * n * CC + c;
    float m = -1e30f, s = 0.f;
    for (int i = blockIdx.x * 256 + threadIdx.x; i < n; i += LSE_CH * 256) {
        float v = p[(size_t)i * CC];
        if (v > m) { s = s * __expf(m - v) + 1.f; m = v; }
        else s += __expf(v - m);
    }
    __shared__ float smm[256], sms[256];
    smm[threadIdx.x] = m; sms[threadIdx.x] = s;
    __syncthreads();
    for (int off = 128; off > 0; off >>= 1) {
        if (threadIdx.x < off) {
            float m2 = smm[threadIdx.x + off], s2 = sms[threadIdx.x + off];
            float M = fmaxf(smm[threadIdx.x], m2);
            sms[threadIdx.x] = sms[threadIdx.x] * __expf(smm[threadIdx.x] - M) + s2 * __expf(m2 - M);
            smm[threadIdx.x] = M;
        }
        __syncthreads();
    }
    if (threadIdx.x == 0) { pm[tc * LSE_CH + blockIdx.x] = smm[0]; ps[tc * LSE_CH + blockIdx.x] = sms[0]; }
}

// final LSE reduction fused into the subtraction kernel: each block re-reduces the
// 8 x 32 partials (2 KB reads/block) into LDS, then subtracts.
__global__ __launch_bounds__(256)
void sub_lse_kernel(const float* __restrict__ logits, const float* __restrict__ pm,
                    const float* __restrict__ ps, float* __restrict__ out, int total, int n) {
    __shared__ float slse[8];
    int tc = threadIdx.x >> 5;        // 8 groups of 32 lanes
    int l32 = threadIdx.x & 31;
    float m = pm[tc * LSE_CH + l32];
    float s = ps[tc * LSE_CH + l32];
    #pragma unroll
    for (int off = 16; off > 0; off >>= 1) {
        float m2 = __shfl_down(m, off, 32);
        float s2 = __shfl_down(s, off, 32);
        float M = fmaxf(m, m2);
        s = s * __expf(m - M) + s2 * __expf(m2 - M);
        m = M;
    }
    if (l32 == 0) slse[tc] = m + logf(s);
    __syncthreads();
    int i = blockIdx.x * 256 + threadIdx.x;
    if (i < total) {
        int c = i & 1;
        int t = i / (n * CC);
        out[i] = logits[i] - slse[t * CC + c];
    }
}

// ---------------- launch ----------------

extern "C" void kernel_launch(void* const* d_in, const int* in_sizes, int n_in,
                              void* d_out, int out_size, void* d_ws, size_t ws_size,
                              hipStream_t stream) {
    const int* graph = (const int*)d_in[0];
    const float* fts = (const float*)d_in[1];
    const float* W1l = (const float*)d_in[3];
    const float* b1  = (const float*)d_in[4];
    const float* W1r = (const float*)d_in[5];
    const float* W2l = (const float*)d_in[6];
    const float* b2  = (const float*)d_in[7];
    const float* W2r = (const float*)d_in[8];
    const float* Wc  = (const float*)d_in[9];
    const float* bc  = (const float*)d_in[10];
    float* out = (float*)d_out;

    const int T = TT;
    const int E = in_sizes[0] / (T * 2);
    const int N = in_sizes[1] / (T * FD);
    const int NBUK = (N + NPB - 1) >> NPB_SHIFT;

    size_t off = 0;
    auto alloc = [&](size_t bytes) -> char* {
        char* p = (char*)d_ws + off;
        off += (bytes + 511) & ~(size_t)511;
        return p;
    };
    int* arr_all = (int*)alloc((size_t)T * N * 4);
    unsigned short* col_all = (unsigned short*)alloc((size_t)T * E * 2);
    int* gcount = (int*)alloc((size_t)T * NBUK * 4);
    unsigned short* wcat1 = (unsigned short*)alloc(128 * 256 * 2);
    unsigned short* wcat2 = (unsigned short*)alloc(128 * 256 * 2);
    float* logits = (float*)alloc((size_t)T * N * CC * 4);
    float* pm  = (float*)alloc((size_t)T * CC * LSE_CH * 4);
    float* ps  = (float*)alloc((size_t)T * CC * LSE_CH * 4);
    // bdata has its own buffer (19.2 MB) so bin and conv are independent
    unsigned int* bdata = (unsigned int*)alloc((size_t)T * NBUK * CAP * 4);
    // t-major feature buffers, 51.2 MB each:
    // R1: xT (prep..gemm1) -> mean2T (agg2..gemm2)
    // R2: mean1T (agg1) -> ysT in-place (gemm1..gemm2)
    unsigned short* R1 = (unsigned short*)alloc((size_t)T * N * FD * 2);
    unsigned short* R2 = (unsigned short*)alloc((size_t)T * N * FD * 2);
    unsigned short* xT = R1;
    unsigned short* mean2T = R1;
    unsigned short* mean1T = R2;
    unsigned short* ysT = R2;

    dim3 pwgrid((128 * 256 + 255) / 256, 2);
    pack_weights_kernel<<<pwgrid, 256, 0, stream>>>(W1l, W1r, W2l, W2r, wcat1, wcat2);

    hipMemsetAsync(gcount, 0, (size_t)T * NBUK * 4, stream);

    // fused bin + conv
    int bpg = (E + BIN_TILE - 1) / BIN_TILE;
    int binBlocks = bpg * T;
    int total8 = T * N * 16;
    int convBlocks = (total8 + 255) / 256;
    prep_kernel<<<binBlocks + convBlocks, 256, 0, stream>>>(
        graph, gcount, bdata, E, NBUK, bpg, binBlocks, fts, xT, total8);

    // build (inline prefix scan over gcount)
    dim3 buildgrid(NBUK, T);
    build_kernel<<<buildgrid, 256, 0, stream>>>(bdata, gcount, arr_all, col_all, N, NBUK, E);

    // layer 1: one agg dispatch (t-major block order), then one 4N-row GEMM
    int bpt = (N + 3) / 4;
    agg_kernel<<<bpt * T, 256, 0, stream>>>(arr_all, col_all, xT, mean1T, N, bpt, N, E);
    int mrows = T * N;
    sage_gemm_kernel<<<(mrows + 255) / 256, 256, 0, stream>>>(mean1T, xT, wcat1, b1, ysT, mrows);

    // layer 2: one agg dispatch with the last graph (stride 0), fused GEMM+classifier
    const int* arrL = arr_all + (size_t)(T - 1) * N;
    const unsigned short* colL = col_all + (size_t)(T - 1) * E;
    agg_kernel<<<bpt * T, 256, 0, stream>>>(arrL, colL, ysT, mean2T, N, bpt, 0, 0);
    gemm2_cls_kernel<<<(mrows + 255) / 256, 256, 0, stream>>>(mean2T, ysT, wcat2, b2,
                                                              Wc, bc, logits, mrows);

    dim3 lgrid(LSE_CH, T * CC);
    lse_partial_kernel<<<lgrid, 256, 0, stream>>>(logits, pm, ps, N);
    int total = T * N * CC;
    sub_lse_kernel<<<(total + 255) / 256, 256, 0, stream>>>(logits, pm, ps, out, total, N);
}